// Round 17
// baseline (639.890 us; speedup 1.0000x reference)
//
#include <hip/hip_runtime.h>

typedef unsigned short u16;
typedef unsigned int u32;
typedef __attribute__((ext_vector_type(8))) short v8s;
typedef __attribute__((ext_vector_type(16))) float f32x16;

#define RPB 128            // rows per block (4 waves x 32 rows)
#define THREADS 256
#define NSB 512            // sort blocks
// u16 offsets inside Wf (32x32x16 fragment order, round-10-verified)
#define W1F 0              // 8 frags (1 k-slice K=16, mt=0..7)  = 4096
#define W2F 4096           // 16 slices x 8 mt                   = 65536
#define W3F 69632          // 16 slices x 8 mt                   = 65536
#define W4F 135168         // 16 slices x 1 frag (out pad 32)    = 8192
#define TOTW 143360
// workspace byte offsets
#define BH_OFF 286720
#define PERM_OFF 305152

#define MFMA32(w, b, c) __builtin_amdgcn_mfma_f32_32x32x16_bf16((w), (b), (c), 0, 0, 0)

typedef __attribute__((address_space(1))) const unsigned int gu32;
typedef __attribute__((address_space(3))) unsigned int su32;
__device__ __forceinline__ void gld16(const u16* g, u16* l) {
  __builtin_amdgcn_global_load_lds((gu32*)g, (su32*)l, 16, 0, 0);
}

__device__ __forceinline__ u32 pk2(float a, float b) {
  u32 r;
  asm("v_cvt_pk_bf16_f32 %0, %1, %2" : "=v"(r) : "v"(a), "v"(b));
  return r;
}
__device__ __forceinline__ float bfu(u32 w, int hi) {
  return __uint_as_float(hi ? (w & 0xffff0000u) : (w << 16));
}
__device__ __forceinline__ float silu1(float x) {
  return x * __builtin_amdgcn_rcpf(1.0f + __expf(-x));
}

// ---------------------------------------------------------------------------
// Weight prep for 32x32x16 (round-10-verified layout + round-15 b1 fold).
// A fragment: lane l holds A[m=l&31][slot(g=l>>5, j=0..7)].
// k-slot permutation: slot (g,j) of k-slice s <-> feature
//   f(s,g,j) = (s>>1)*32 + (s&1)*16 + (j>>2)*8 + 4*g + (j&3)
// so producer D regs map: bact[2mt]=acc[mt] regs0-7, bact[2mt+1]=regs8-15
// (D layout col=lane&31, row=(reg&3)+8(reg>>2)+4g).
// W1: 1 slice; f 0-5 = hi, 6-11 = lo dup, 12 = b1 (const-1 input), 13-15 = 0.
// W4: out-features padded 4->32.
// ---------------------------------------------------------------------------
__global__ void prep_weights(const float* __restrict__ W1, const float* __restrict__ b1,
                             const float* __restrict__ W2, const float* __restrict__ W3,
                             const float* __restrict__ W4, u16* __restrict__ Wf) {
  int e = blockIdx.x * 256 + threadIdx.x;
  if (e >= TOTW) return;
  float val = 0.0f;
  if (e < W2F) {                       // W1: [mt][lane][j]
    int mt = e >> 9, idx = e & 511, l = idx >> 3, j = idx & 7;
    int g = l >> 5, m = l & 31;
    int f = ((j >> 2) << 3) + (g << 2) + (j & 3);     // 0..15
    int col = mt * 32 + m;
    val = (f < 6) ? W1[f * 256 + col]
        : ((f < 12) ? W1[(f - 6) * 256 + col]
        : ((f == 12) ? b1[col] : 0.0f));
  } else if (e < W3F) {                // W2: [s][mt][lane][j]
    int e2 = e - W2F, blk = e2 >> 9, idx = e2 & 511, l = idx >> 3, j = idx & 7;
    int s = blk >> 3, mt = blk & 7, g = l >> 5, m = l & 31;
    int f = ((s >> 1) << 5) + ((s & 1) << 4) + ((j >> 2) << 3) + (g << 2) + (j & 3);
    val = W2[f * 256 + mt * 32 + m];
  } else if (e < W4F) {                // W3
    int e2 = e - W3F, blk = e2 >> 9, idx = e2 & 511, l = idx >> 3, j = idx & 7;
    int s = blk >> 3, mt = blk & 7, g = l >> 5, m = l & 31;
    int f = ((s >> 1) << 5) + ((s & 1) << 4) + ((j >> 2) << 3) + (g << 2) + (j & 3);
    val = W3[f * 256 + mt * 32 + m];
  } else {                             // W4: [s][lane][j], out 4 -> 32 pad
    int e2 = e - W4F, s = e2 >> 9, idx = e2 & 511, l = idx >> 3, j = idx & 7;
    int g = l >> 5, m = l & 31;
    int f = ((s >> 1) << 5) + ((s & 1) << 4) + ((j >> 2) << 3) + (g << 2) + (j & 3);
    val = (m < 4) ? W4[f * 4 + m] : 0.0f;
  }
  Wf[e] = (u16)pk2(val, val);
}

// ------------------ counting sort by n_full (LDS-local) ---------------------
__global__ void hist_blocks(const float* __restrict__ zf, int* __restrict__ bh, int B) {
  __shared__ int h[9];
  int t = threadIdx.x;
  if (t < 9) h[t] = 0;
  __syncthreads();
  int r = blockIdx.x * 512 + t;
  if (r < B) {
    int nf = min(max((int)floorf(zf[r] * 8.0f), 0), 8);
    atomicAdd(&h[nf], 1);
  }
  __syncthreads();
  if (t < 9) bh[blockIdx.x * 9 + t] = h[t];
}

__global__ void scan_offsets(int* __restrict__ bh) {
  __shared__ int S[NSB * 9];
  __shared__ int tot[9], ebase[9];
  int t = threadIdx.x;
  for (int i = t; i < NSB * 9; i += 512) S[i] = bh[i];
  __syncthreads();
  if (t < 9) {
    int s = 0;
    for (int b = 0; b < NSB; ++b) s += S[b * 9 + t];
    tot[t] = s;
  }
  __syncthreads();
  if (t == 0) {
    int s = 0;
    for (int i = 0; i < 9; ++i) { ebase[i] = s; s += tot[i]; }
  }
  __syncthreads();
  if (t < 9) {
    int off = ebase[t];
    for (int b = 0; b < NSB; ++b) { int c = S[b * 9 + t]; S[b * 9 + t] = off; off += c; }
  }
  __syncthreads();
  for (int i = t; i < NSB * 9; i += 512) bh[i] = S[i];
}

__global__ void scatter_sorted(const float* __restrict__ zf, const int* __restrict__ bh,
                               int* __restrict__ perm, int B) {
  __shared__ int off[9];
  int t = threadIdx.x;
  if (t < 9) off[t] = bh[blockIdx.x * 9 + t];
  __syncthreads();
  int r = blockIdx.x * 512 + t;
  if (r < B) {
    int nf = min(max((int)floorf(zf[r] * 8.0f), 0), 8);
    int pos = atomicAdd(&off[nf], 1);
    perm[pos] = r;
  }
}

// ---------------------------------------------------------------------------
// Main kernel: 32x32x16 MFMA, 4 waves x 32 rows. 2x FLOPs per LDS fragment
// read vs round 16 (LDS-read wall 403 -> ~200us). Register discipline:
// acc[8] f32x16 = 128 AGPRs (waves_per_eu(2,2): 128 arch + 128 AGPR);
// arch side = bact[16] 64 + capped w-temps 16 + misc ~40 < 128 -> no spill.
// No BINIT (round-10's spill source): acc zero-init, bias in the silu pack;
// b1 folded into W1 via const-1 feature. Ring: 3 x 16KB (2 k-slices/phase,
// 16 ds_read + 16 MFMA), issue-ahead-1, counted vmcnt(4), 16 barriers/eval.
// ---------------------------------------------------------------------------
__global__ __attribute__((amdgpu_flat_work_group_size(256, 256)))
__attribute__((amdgpu_waves_per_eu(2, 2))) void pinn_main(
    const float* __restrict__ sdz, const float* __restrict__ zf,
    const u16* __restrict__ Wf, const int* __restrict__ perm,
    const float* __restrict__ b2, const float* __restrict__ b3,
    const float* __restrict__ b4, float* __restrict__ out) {
  __shared__ __align__(16) u16 ringS[3][8192];   // 48 KB: 3 x 16KB (2 slices)
  __shared__ __align__(16) u16 W1s[4096];        // 8 KB
  __shared__ __align__(16) u16 W4s[8192];        // 16 KB
  __shared__ __align__(16) float biasS[520];     // b2|b3|b4
  __shared__ __align__(16) float stS[RPB * 4];
  __shared__ float qopS[RPB], dzS[RPB], fracS[RPB];
  __shared__ int nfS[RPB], rowG[RPB];

  const int t = threadIdx.x;
  const int lane = t & 63;
  const int g = lane >> 5;    // k-slot half / D row sub-block
  const int g4 = g << 2;
  const int n32 = lane & 31;  // batch column within tile
  const int wv = t >> 6;      // 0..3
  const int rb = wv * 32;     // wave's first block-local row

  if (t < RPB) {
    int rg = perm[blockIdx.x * RPB + t];
    rowG[t] = rg;
    const float* p = sdz + (size_t)rg * 6;
    stS[t * 4 + 0] = p[0]; stS[t * 4 + 1] = p[1];
    stS[t * 4 + 2] = p[2]; stS[t * 4 + 3] = p[3];
    qopS[t] = p[4];
    dzS[t] = p[5] * 0.125f;
    float cs = zf[rg] * 8.0f;
    float nfl = floorf(cs);
    nfS[t] = (int)nfl;
    fracS[t] = cs - nfl;
  }
  biasS[t] = b2[t]; biasS[256 + t] = b3[t];
  if (t < 8) biasS[512 + t] = (t < 4) ? b4[t] : 0.0f;
  // stage W1 (8 chunks: 4 waves x 2) and W4 (16 chunks: 4 waves x 4)
#pragma unroll
  for (int c = 0; c < 2; ++c)
    gld16(Wf + W1F + (c * 4 + wv) * 512 + lane * 8, &W1s[(c * 4 + wv) * 512]);
#pragma unroll
  for (int c = 0; c < 4; ++c)
    gld16(Wf + W4F + (c * 4 + wv) * 512 + lane * 8, &W4s[(c * 4 + wv) * 512]);
  __syncthreads();
  const int maxnf = nfS[RPB - 1];   // rows sorted by n_full

  f32x16 acc[8];
  v8s bact[16];

  // ---- ring: phase ap covers 2 k-slices (16KB); [layer:1][ph:3] = ap&15 ----
#define ISSUE_SLICE(AP, BUF)                                                  \
  do {                                                                        \
    int sp_ = (AP) & 15;                                                      \
    int off_ = ((sp_ >> 3) ? W3F : W2F) + (sp_ & 7) * 8192;                   \
    u16* dst_ = &ringS[(BUF)][0];                                             \
    _Pragma("unroll") for (int c_ = 0; c_ < 4; ++c_)                          \
      gld16(Wf + off_ + (c_ * 4 + wv) * 512 + lane * 8,                       \
            dst_ + (c_ * 4 + wv) * 512);                                      \
  } while (0)

  int ap = 0;   // next phase to consume
  int bc = 0;   // its ring buffer
  ISSUE_SLICE(0, 0);

#define ZACC(A)                                                     \
  do {                                                              \
    _Pragma("unroll") for (int i_ = 0; i_ < 16; ++i_) (A)[i_] = 0.0f; \
  } while (0)

#define PACK_CORE(MT)                                               \
  do {                                                              \
    union { int4 i4; v8s v; } lo_, hi_;                             \
    lo_.i4.x = (int)pk2(s_[0], s_[1]);                              \
    lo_.i4.y = (int)pk2(s_[2], s_[3]);                              \
    lo_.i4.z = (int)pk2(s_[4], s_[5]);                              \
    lo_.i4.w = (int)pk2(s_[6], s_[7]);                              \
    hi_.i4.x = (int)pk2(s_[8], s_[9]);                              \
    hi_.i4.y = (int)pk2(s_[10], s_[11]);                            \
    hi_.i4.z = (int)pk2(s_[12], s_[13]);                            \
    hi_.i4.w = (int)pk2(s_[14], s_[15]);                            \
    bact[2 * (MT)] = lo_.v;                                         \
    bact[2 * (MT) + 1] = hi_.v;                                     \
  } while (0)

  // no-bias pack (L1 output; b1 folded into W1 via const-1 feature)
#define PACK_NB()                                                   \
  do {                                                              \
    _Pragma("unroll") for (int mt = 0; mt < 8; ++mt) {              \
      float s_[16];                                                 \
      _Pragma("unroll") for (int i_ = 0; i_ < 16; ++i_)             \
        s_[i_] = silu1(acc[mt][i_]);                                \
      PACK_CORE(mt);                                                \
    }                                                               \
  } while (0)

  // bias pack: reg r=4rq+ri of acc[mt] -> feature mt*32 + 8*rq + 4*g + ri
#define PACK_B(LB)                                                  \
  do {                                                              \
    _Pragma("unroll") for (int mt = 0; mt < 8; ++mt) {              \
      float s_[16];                                                 \
      _Pragma("unroll") for (int rq = 0; rq < 4; ++rq) {            \
        const float4 bb =                                           \
            *(const float4*)&biasS[(LB) + mt * 32 + rq * 8 + g4];   \
        s_[4 * rq + 0] = silu1(acc[mt][4 * rq + 0] + bb.x);         \
        s_[4 * rq + 1] = silu1(acc[mt][4 * rq + 1] + bb.y);         \
        s_[4 * rq + 2] = silu1(acc[mt][4 * rq + 2] + bb.z);         \
        s_[4 * rq + 3] = silu1(acc[mt][4 * rq + 3] + bb.w);         \
      }                                                             \
      PACK_CORE(mt);                                                \
    }                                                               \
  } while (0)

  for (int ev = 0; ev <= maxnf; ++ev) {
    const bool partial = (ev == maxnf);

    // ---- layer-1 B-fragment: slot(g,j) = feature (j>>2)*8+4g+(j&3);
    //      g==1 slot j=4 is f=12 -> const 1.0 (b1 row in W1) ----
    v8s b1f;
    {
      const int row = rb + n32;
      const float4 st = *(const float4*)&stS[row * 4];
      const float qop = qopS[row];
      const float dzv = partial ? fracS[row] * dzS[row] : dzS[row];
      u32 h01 = pk2(st.x, st.y), h23 = pk2(st.z, st.w), hqd = pk2(qop, dzv);
      float l0 = st.x - bfu(h01, 0), l1 = st.y - bfu(h01, 1);
      float l2 = st.z - bfu(h23, 0), l3 = st.w - bfu(h23, 1);
      float lq = qop - bfu(hqd, 0), ld = dzv - bfu(hqd, 1);
      union { int4 i4; v8s v; } u_;
      if (g == 0) {   // f 0-3 (hi st), f 8-11 (lo st2,st3,qop,dz)
        u_.i4.x = (int)h01; u_.i4.y = (int)h23;
        u_.i4.z = (int)pk2(l2, l3); u_.i4.w = (int)pk2(lq, ld);
      } else {        // f 4-7 (hi qop,dz; lo st0,st1), f 12 = 1.0, 13-15 = 0
        u_.i4.x = (int)hqd; u_.i4.y = (int)pk2(l0, l1);
        u_.i4.z = (int)0x00003F80u; u_.i4.w = 0;
      }
      b1f = u_.v;
    }

    // ---- L1: acc[mt] = W1^T @ [x,1] (one K=16 slice, zero C) ----
#pragma unroll
    for (int mt = 0; mt < 8; ++mt) {
      const v8s w = *(const v8s*)&W1s[mt * 512 + lane * 8];
      f32x16 z;
      ZACC(z);
      acc[mt] = MFMA32(w, b1f, z);
      if ((mt & 3) == 3) __builtin_amdgcn_sched_barrier(0);
    }
    PACK_NB();

    // ---- L2, L3: 8 phases each (2 k-slices/phase), counted-vmcnt ring ----
#pragma unroll
    for (int layer = 0; layer < 2; ++layer) {
#pragma unroll
      for (int mt = 0; mt < 8; ++mt) ZACC(acc[mt]);
#pragma unroll
      for (int ph = 0; ph < 8; ++ph) {
        int bn = bc + 1; if (bn == 3) bn = 0;
        ISSUE_SLICE(ap + 1, bn);                 // 4 gld16 -> in flight
        asm volatile("s_waitcnt vmcnt(4)" ::: "memory");  // own phase loaded
        __builtin_amdgcn_sched_barrier(0);
        __builtin_amdgcn_s_barrier();            // publish; NO vmcnt(0) drain
        __builtin_amdgcn_sched_barrier(0);
        asm volatile("" ::: "memory");
        const u16* buf = &ringS[bc][0];
        __builtin_amdgcn_s_setprio(1);
#pragma unroll
        for (int h = 0; h < 2; ++h) {
          const v8s ba = bact[ph * 2 + h];
#pragma unroll
          for (int mt = 0; mt < 8; ++mt) {
            const v8s w = *(const v8s*)&buf[(h * 8 + mt) * 512 + lane * 8];
            acc[mt] = MFMA32(w, ba, acc[mt]);
            if ((mt & 3) == 3) __builtin_amdgcn_sched_barrier(0);
          }
        }
        __builtin_amdgcn_s_setprio(0);
        bc = bn; ++ap;
      }
      if (layer == 0) PACK_B(0); else PACK_B(256);
    }

    // ---- L4 (out padded 4->32) + masked state update ----
    {
      f32x16 a4;
      ZACC(a4);
#pragma unroll
      for (int s = 0; s < 16; ++s) {
        const v8s w = *(const v8s*)&W4s[s * 512 + lane * 8];
        a4 = MFMA32(w, bact[s], a4);
        if ((s & 3) == 3) __builtin_amdgcn_sched_barrier(0);
      }
      // g==0 lanes hold out features 0..3 in regs 0..3 for row rb+n32
      if (g == 0) {
        const int row = rb + n32;
        const bool act = partial ? (fracS[row] > 1e-6f) : (nfS[row] > ev);
        if (act) {
          float4 cur = *(float4*)&stS[row * 4];
          cur.x += a4[0] + biasS[512];
          cur.y += a4[1] + biasS[513];
          cur.z += a4[2] + biasS[514];
          cur.w += a4[3] + biasS[515];
          *(float4*)&stS[row * 4] = cur;
        }
      }
    }
  }
  __syncthreads();   // drains remaining ring prefetch + stS visibility

  // scattered output write (16B per row, rows permuted)
#pragma unroll
  for (int i = t; i < RPB * 4; i += THREADS)
    out[(size_t)rowG[i >> 2] * 4 + (i & 3)] = stS[i];
}

extern "C" void kernel_launch(void* const* d_in, const int* in_sizes, int n_in,
                              void* d_out, int out_size, void* d_ws, size_t ws_size,
                              hipStream_t stream) {
  const float* sdz = (const float*)d_in[0];
  const float* zfr = (const float*)d_in[1];
  const float* W1 = (const float*)d_in[2];
  const float* b1 = (const float*)d_in[3];
  const float* W2 = (const float*)d_in[4];
  const float* b2 = (const float*)d_in[5];
  const float* W3 = (const float*)d_in[6];
  const float* b3 = (const float*)d_in[7];
  const float* W4 = (const float*)d_in[8];
  const float* b4 = (const float*)d_in[9];

  char* ws = (char*)d_ws;
  u16* Wf = (u16*)ws;
  int* bh = (int*)(ws + BH_OFF);
  int* perm = (int*)(ws + PERM_OFF);

  const int B = in_sizes[1];   // 262144

  prep_weights<<<(TOTW + 255) / 256, 256, 0, stream>>>(W1, b1, W2, W3, W4, Wf);
  hist_blocks<<<NSB, 512, 0, stream>>>(zfr, bh, B);
  scan_offsets<<<1, 512, 0, stream>>>(bh);
  scatter_sorted<<<NSB, 512, 0, stream>>>(zfr, bh, perm, B);
  pinn_main<<<B / RPB, THREADS, 0, stream>>>(sdz, zfr, Wf, perm, b2, b3, b4,
                                             (float*)d_out);
}

// Round 18
// 553.026 us; speedup vs baseline: 1.1571x; 1.1571x over previous
//
#include <hip/hip_runtime.h>

typedef unsigned short u16;
typedef unsigned int u32;
typedef __attribute__((ext_vector_type(8))) short v8s;
typedef __attribute__((ext_vector_type(4))) float f32x4;

#define RPB 64             // rows per block (4 waves x 16 rows)
#define THREADS 256
#define NSB 512            // sort blocks
// u16 offsets inside Wf
#define W1F 0
#define W2F 8192
#define W3F 73728
#define W4F 139264
#define TOTW 143360
// workspace byte offsets
#define BH_OFF 286720
#define PERM_OFF 305152

#define MFMA(w, b, c) __builtin_amdgcn_mfma_f32_16x16x32_bf16((w), (b), (c), 0, 0, 0)

typedef __attribute__((address_space(1))) const unsigned int gu32;
typedef __attribute__((address_space(3))) unsigned int su32;
__device__ __forceinline__ void gld16(const u16* g, u16* l) {
  __builtin_amdgcn_global_load_lds((gu32*)g, (su32*)l, 16, 0, 0);
}

__device__ __forceinline__ u32 pk2(float a, float b) {
  u32 r;
  asm("v_cvt_pk_bf16_f32 %0, %1, %2" : "=v"(r) : "v"(a), "v"(b));
  return r;
}
__device__ __forceinline__ float bfu(u32 w, int hi) {
  return __uint_as_float(hi ? (w & 0xffff0000u) : (w << 16));
}
__device__ __forceinline__ f32x4 silu4(f32x4 v) {
  f32x4 r;
#pragma unroll
  for (int i = 0; i < 4; ++i) r[i] = v[i] * __builtin_amdgcn_rcpf(1.0f + __expf(-v[i]));
  return r;
}

// ---------------------------------------------------------------------------
// Weight prep (round-16-proven): bf16, A-fragment order, k-slot permutation
// slot(q,j) <-> feature f = 32ks+16*(j>>2)+4q+(j&3).
// W1: K 12->32; f6..11 dup hi/lo; f12 = b1 (const-1 input folds layer-1 bias).
// W4: out-features padded 4->16. W2/W3 slice-major: (ks*16+mt)*512.
// ---------------------------------------------------------------------------
__global__ void prep_weights(const float* __restrict__ W1, const float* __restrict__ b1,
                             const float* __restrict__ W2, const float* __restrict__ W3,
                             const float* __restrict__ W4, u16* __restrict__ Wf) {
  int e = blockIdx.x * 256 + threadIdx.x;
  if (e >= TOTW) return;
  float val = 0.0f;
  if (e < W2F) {
    int mt = e >> 9, idx = e & 511, l = idx >> 3, j = idx & 7;
    int q = l >> 4, m = l & 15;
    int f = 16 * (j >> 2) + 4 * q + (j & 3);
    int col = mt * 16 + m;
    val = (f < 6) ? W1[f * 256 + col]
        : ((f < 12) ? W1[(f - 6) * 256 + col]
        : ((f == 12) ? b1[col] : 0.0f));
  } else if (e < W3F) {
    int e2 = e - W2F, blk = e2 >> 9, idx = e2 & 511, l = idx >> 3, j = idx & 7;
    int ks = blk >> 4, mt = blk & 15, q = l >> 4, m = l & 15;
    int f = 32 * ks + 16 * (j >> 2) + 4 * q + (j & 3);
    val = W2[f * 256 + mt * 16 + m];
  } else if (e < W4F) {
    int e2 = e - W3F, blk = e2 >> 9, idx = e2 & 511, l = idx >> 3, j = idx & 7;
    int ks = blk >> 4, mt = blk & 15, q = l >> 4, m = l & 15;
    int f = 32 * ks + 16 * (j >> 2) + 4 * q + (j & 3);
    val = W3[f * 256 + mt * 16 + m];
  } else {
    int e2 = e - W4F, ks = e2 >> 9, idx = e2 & 511, l = idx >> 3, j = idx & 7;
    int q = l >> 4, m = l & 15;
    int f = 32 * ks + 16 * (j >> 2) + 4 * q + (j & 3);
    val = (m < 4) ? W4[f * 4 + m] : 0.0f;
  }
  Wf[e] = (u16)pk2(val, val);
}

// ------------------ counting sort by n_full (LDS-local) ---------------------
__global__ void hist_blocks(const float* __restrict__ zf, int* __restrict__ bh, int B) {
  __shared__ int h[9];
  int t = threadIdx.x;
  if (t < 9) h[t] = 0;
  __syncthreads();
  int r = blockIdx.x * 512 + t;
  if (r < B) {
    int nf = min(max((int)floorf(zf[r] * 8.0f), 0), 8);
    atomicAdd(&h[nf], 1);
  }
  __syncthreads();
  if (t < 9) bh[blockIdx.x * 9 + t] = h[t];
}

__global__ void scan_offsets(int* __restrict__ bh) {
  __shared__ int S[NSB * 9];
  __shared__ int tot[9], ebase[9];
  int t = threadIdx.x;
  for (int i = t; i < NSB * 9; i += 512) S[i] = bh[i];
  __syncthreads();
  if (t < 9) {
    int s = 0;
    for (int b = 0; b < NSB; ++b) s += S[b * 9 + t];
    tot[t] = s;
  }
  __syncthreads();
  if (t == 0) {
    int s = 0;
    for (int i = 0; i < 9; ++i) { ebase[i] = s; s += tot[i]; }
  }
  __syncthreads();
  if (t < 9) {
    int off = ebase[t];
    for (int b = 0; b < NSB; ++b) { int c = S[b * 9 + t]; S[b * 9 + t] = off; off += c; }
  }
  __syncthreads();
  for (int i = t; i < NSB * 9; i += 512) bh[i] = S[i];
}

__global__ void scatter_sorted(const float* __restrict__ zf, const int* __restrict__ bh,
                               int* __restrict__ perm, int B) {
  __shared__ int off[9];
  int t = threadIdx.x;
  if (t < 9) off[t] = bh[blockIdx.x * 9 + t];
  __syncthreads();
  int r = blockIdx.x * 512 + t;
  if (r < B) {
    int nf = min(max((int)floorf(zf[r] * 8.0f), 0), 8);
    int pos = atomicAdd(&off[nf], 1);
    perm[pos] = r;
  }
}

// ---------------------------------------------------------------------------
// Main kernel: round-16 structure (4 waves x 16 rows, acc 64 + bact 32 +
// temps ~ 126 arch regs = no-spill cap at 256/min_waves=128) with W1/W4
// STREAMED through the ring: per-eval phase stream [W1][W2 s0..7][W3 s0..7]
// [W4], 18 phases, 3 x 16KB slots (18 % 3 == 0 -> eval-invariant mapping).
// LDS 53.2 KB -> 3 blocks/CU; waves_per_eu(2,3): min=2 keeps the 128-reg
// cap, max=3 allows 12 waves/CU (round 16 was LDS+attr-capped at 8).
// Counted vmcnt: 4, or 2 when the just-issued next phase is the 8KB W4.
// ---------------------------------------------------------------------------
__global__ __attribute__((amdgpu_flat_work_group_size(256, 256)))
__attribute__((amdgpu_waves_per_eu(2, 3))) void pinn_main(
    const float* __restrict__ sdz, const float* __restrict__ zf,
    const u16* __restrict__ Wf, const int* __restrict__ perm,
    const float* __restrict__ b2, const float* __restrict__ b3,
    const float* __restrict__ b4, float* __restrict__ out) {
  __shared__ __align__(16) u16 ringS[3][8192];   // 48 KB: 3 x 16KB slots
  __shared__ __align__(16) float biasS[528];     // b2|b3|b4-padded
  __shared__ __align__(16) float stS[RPB * 4];
  __shared__ float qopS[RPB], dzS[RPB], dzpS[RPB];
  __shared__ u16 nfS[RPB];                       // nf | (has_partial<<8)

  const int t = threadIdx.x;
  const int lane = t & 63;
  const int q = lane >> 4;    // k-slot group / D row-block
  const int n = lane & 15;    // batch column within tile
  const int wv = t >> 6;      // 0..3
  const int rb = wv * 16;     // wave's first block-local row

  if (t < RPB) {
    int rg = perm[blockIdx.x * RPB + t];
    const float* p = sdz + (size_t)rg * 6;
    stS[t * 4 + 0] = p[0]; stS[t * 4 + 1] = p[1];
    stS[t * 4 + 2] = p[2]; stS[t * 4 + 3] = p[3];
    qopS[t] = p[4];
    float dzsub = p[5] * 0.125f;
    dzS[t] = dzsub;
    float cs = zf[rg] * 8.0f;
    float nfl = floorf(cs);
    float fr = cs - nfl;
    dzpS[t] = fr * dzsub;
    nfS[t] = (u16)((int)nfl | ((fr > 1e-6f) ? 256 : 0));
  }
  biasS[t] = b2[t]; biasS[256 + t] = b3[t];
  if (t < 16) biasS[512 + t] = (t < 4) ? b4[t] : 0.0f;

#define ISSUE16(OFF, BUF)                                                     \
  do {                                                                        \
    u16* dst_ = &ringS[(BUF)][0];                                             \
    _Pragma("unroll") for (int c_ = 0; c_ < 4; ++c_)                          \
      gld16(Wf + (OFF) + (c_ * 4 + wv) * 512 + lane * 8,                      \
            dst_ + (c_ * 4 + wv) * 512);                                      \
  } while (0)
#define ISSUE8(OFF, BUF)                                                      \
  do {                                                                        \
    u16* dst_ = &ringS[(BUF)][0];                                             \
    _Pragma("unroll") for (int c_ = 0; c_ < 2; ++c_)                          \
      gld16(Wf + (OFF) + (c_ * 4 + wv) * 512 + lane * 8,                      \
            dst_ + (c_ * 4 + wv) * 512);                                      \
  } while (0)

#define PHASE_SYNC4()                                                         \
  asm volatile("s_waitcnt vmcnt(4)" ::: "memory");                            \
  __builtin_amdgcn_sched_barrier(0);                                          \
  __builtin_amdgcn_s_barrier();                                               \
  __builtin_amdgcn_sched_barrier(0);                                          \
  asm volatile("" ::: "memory");
#define PHASE_SYNC2()                                                         \
  asm volatile("s_waitcnt vmcnt(2)" ::: "memory");                            \
  __builtin_amdgcn_sched_barrier(0);                                          \
  __builtin_amdgcn_s_barrier();                                               \
  __builtin_amdgcn_sched_barrier(0);                                          \
  asm volatile("" ::: "memory");

  ISSUE16(W1F, 0);   // prologue: first W1 into slot 0
  __syncthreads();
  const int maxnf = nfS[RPB - 1] & 255;   // rows sorted by n_full
  int bc = 0;

  f32x4 acc[16];
  v8s bact[8];
  const f32x4 Z4 = {0.0f, 0.0f, 0.0f, 0.0f};

#define PACK_BACT()                                              \
  do {                                                           \
    _Pragma("unroll") for (int ks = 0; ks < 8; ++ks) {           \
      f32x4 a0 = silu4(acc[2 * ks]);                             \
      f32x4 a1 = silu4(acc[2 * ks + 1]);                         \
      union { int4 i; v8s s; } u_;                               \
      u_.i.x = (int)pk2(a0[0], a0[1]);                           \
      u_.i.y = (int)pk2(a0[2], a0[3]);                           \
      u_.i.z = (int)pk2(a1[0], a1[1]);                           \
      u_.i.w = (int)pk2(a1[2], a1[3]);                           \
      bact[ks] = u_.s;                                           \
    }                                                            \
  } while (0)

  for (int ev = 0; ev <= maxnf; ++ev) {
    const bool partial = (ev == maxnf);

    // ---- layer-1 B-fragment: hi/lo split + const-1 slot (f=12, q=3) ----
    v8s b1f;
    {
      const int row = rb + n;
      const float4 st = *(const float4*)&stS[row * 4];
      const float qop = qopS[row];
      const float dzv = partial ? dzpS[row] : dzS[row];
      u32 h01 = pk2(st.x, st.y), h23 = pk2(st.z, st.w), hqd = pk2(qop, dzv);
      float l0 = st.x - bfu(h01, 0), l1 = st.y - bfu(h01, 1);
      float l2 = st.z - bfu(h23, 0), l3 = st.w - bfu(h23, 1);
      float lq = qop - bfu(hqd, 0), ld = dzv - bfu(hqd, 1);
      u32 w0 = 0, w1 = 0;
      if (q == 0) { w0 = h01; w1 = h23; }
      else if (q == 1) { w0 = hqd; w1 = pk2(l0, l1); }
      else if (q == 2) { w0 = pk2(l2, l3); w1 = pk2(lq, ld); }
      else { w0 = 0x00003F80u; }   // f=12 slot = 1.0 -> W1 row 12 = b1
      union { int4 i; v8s s; } u_;
      u_.i.x = (int)w0; u_.i.y = (int)w1; u_.i.z = 0; u_.i.w = 0;
      b1f = u_.s;
    }

    // ---- L1 phase: consume W1 slot; prefetch W2 s0 ----
    {
      int bn = bc + 1; if (bn == 3) bn = 0;
      ISSUE16(W2F, bn);
      PHASE_SYNC4();
      const u16* buf = &ringS[bc][0];
      __builtin_amdgcn_s_setprio(1);
#pragma unroll
      for (int mt = 0; mt < 8; ++mt) {
        const v8s w = *(const v8s*)&buf[mt * 512 + lane * 8];
        acc[mt] = MFMA(w, b1f, Z4);
      }
      __builtin_amdgcn_sched_barrier(0);
#pragma unroll
      for (int mt = 8; mt < 16; ++mt) {
        const v8s w = *(const v8s*)&buf[mt * 512 + lane * 8];
        acc[mt] = MFMA(w, b1f, Z4);
      }
      __builtin_amdgcn_s_setprio(0);
      bc = bn;
    }
    PACK_BACT();

    // ---- L2, L3: 8 phases each (one 16KB k-slice per barrier) ----
#pragma unroll
    for (int layer = 0; layer < 2; ++layer) {
      const int Lb = (layer == 0) ? 0 : 256;
#pragma unroll
      for (int mt = 0; mt < 16; ++mt) {
        const float4 bb = *(const float4*)&biasS[Lb + mt * 16 + q * 4];
        const f32x4 binit = {bb.x, bb.y, bb.z, bb.w};
        acc[mt] = binit;
      }
#pragma unroll
      for (int ph = 0; ph < 8; ++ph) {
        int bn = bc + 1; if (bn == 3) bn = 0;
        if (layer == 1 && ph == 7) {
          ISSUE8(W4F, bn);          // next phase = W4 (8KB, 2 loads/wave)
          PHASE_SYNC2();
        } else {
          const int noff = (ph < 7) ? ((layer ? W3F : W2F) + (ph + 1) * 8192)
                                    : W3F;   // layer 0 ph 7 -> W3 s0
          ISSUE16(noff, bn);
          PHASE_SYNC4();
        }
        const u16* buf = &ringS[bc][0];
        __builtin_amdgcn_s_setprio(1);
#pragma unroll
        for (int i = 0; i < 8; ++i) {
          const v8s w = *(const v8s*)&buf[i * 512 + lane * 8];
          acc[i] = MFMA(w, bact[ph], acc[i]);
        }
        __builtin_amdgcn_sched_barrier(0);   // cap w-temp liveness at 8
#pragma unroll
        for (int i = 8; i < 16; ++i) {
          const v8s w = *(const v8s*)&buf[i * 512 + lane * 8];
          acc[i] = MFMA(w, bact[ph], acc[i]);
        }
        __builtin_amdgcn_s_setprio(0);
        bc = bn;
      }
      PACK_BACT();
    }

    // ---- L4 phase: consume W4 slot; prefetch next eval's W1 ----
    {
      int bn = bc + 1; if (bn == 3) bn = 0;
      ISSUE16(W1F, bn);
      PHASE_SYNC4();
      const u16* buf = &ringS[bc][0];
      const float4 bb = *(const float4*)&biasS[512 + q * 4];
      f32x4 a4 = {bb.x, bb.y, bb.z, bb.w};
      __builtin_amdgcn_s_setprio(1);
#pragma unroll
      for (int ks = 0; ks < 8; ++ks) {
        const v8s w = *(const v8s*)&buf[ks * 512 + lane * 8];
        a4 = MFMA(w, bact[ks], a4);
      }
      __builtin_amdgcn_s_setprio(0);
      if (q == 0) {
        const int row = rb + n;
        const u16 nfv = nfS[row];
        const bool act = partial ? (nfv >> 8) : ((nfv & 255) > ev);
        if (act) {
          float4 cur = *(float4*)&stS[row * 4];
          cur.x += a4[0]; cur.y += a4[1];
          cur.z += a4[2]; cur.w += a4[3];
          *(float4*)&stS[row * 4] = cur;
        }
      }
      bc = bn;
    }
  }
  __syncthreads();   // drains remaining ring prefetch + stS visibility

  // scattered output write (16B per row; re-read perm, rowG not stored)
  {
    int r = perm[blockIdx.x * RPB + (t >> 2)];
    out[(size_t)r * 4 + (t & 3)] = stS[t];
  }
}

extern "C" void kernel_launch(void* const* d_in, const int* in_sizes, int n_in,
                              void* d_out, int out_size, void* d_ws, size_t ws_size,
                              hipStream_t stream) {
  const float* sdz = (const float*)d_in[0];
  const float* zfr = (const float*)d_in[1];
  const float* W1 = (const float*)d_in[2];
  const float* b1 = (const float*)d_in[3];
  const float* W2 = (const float*)d_in[4];
  const float* b2 = (const float*)d_in[5];
  const float* W3 = (const float*)d_in[6];
  const float* b3 = (const float*)d_in[7];
  const float* W4 = (const float*)d_in[8];
  const float* b4 = (const float*)d_in[9];

  char* ws = (char*)d_ws;
  u16* Wf = (u16*)ws;
  int* bh = (int*)(ws + BH_OFF);
  int* perm = (int*)(ws + PERM_OFF);

  const int B = in_sizes[1];   // 262144

  prep_weights<<<(TOTW + 255) / 256, 256, 0, stream>>>(W1, b1, W2, W3, W4, Wf);
  hist_blocks<<<NSB, 512, 0, stream>>>(zfr, bh, B);
  scan_offsets<<<1, 512, 0, stream>>>(bh);
  scatter_sorted<<<NSB, 512, 0, stream>>>(zfr, bh, perm, B);
  pinn_main<<<B / RPB, THREADS, 0, stream>>>(sdz, zfr, Wf, perm, b2, b3, b4,
                                             (float*)d_out);
}